// Round 1
// baseline (520.816 us; speedup 1.0000x reference)
//
#include <hip/hip_runtime.h>
#include <float.h>

#define NN 100000
#define NE 1600000

// ---------------- CSR build ----------------

__global__ void k_zero_int(int* __restrict__ p, int n) {
  int i = blockIdx.x * blockDim.x + threadIdx.x;
  if (i < n) p[i] = 0;
}

__global__ void k_count(const int* __restrict__ dst, int* __restrict__ cnt) {
  int i = blockIdx.x * blockDim.x + threadIdx.x;
  if (i < NE) atomicAdd(&cnt[dst[i]], 1);
}

// Pass A: per-1024-chunk inclusive scan. Writes inclusive values to rowptr[i+1],
// chunk totals to partial[b].
__global__ void k_scan1(const int* __restrict__ cnt, int* __restrict__ rowptr,
                        int* __restrict__ partial, int n) {
  __shared__ int sdata[256];
  int t = threadIdx.x;
  int base = blockIdx.x * 1024 + t * 4;
  int v[4];
  int s = 0;
#pragma unroll
  for (int k = 0; k < 4; k++) {
    int i = base + k;
    v[k] = (i < n) ? cnt[i] : 0;
    s += v[k];
  }
  sdata[t] = s;
  __syncthreads();
  for (int off = 1; off < 256; off <<= 1) {
    int x = (t >= off) ? sdata[t - off] : 0;
    __syncthreads();
    sdata[t] += x;
    __syncthreads();
  }
  int run = sdata[t] - s;  // exclusive prefix of this thread's 4 items
#pragma unroll
  for (int k = 0; k < 4; k++) {
    int i = base + k;
    run += v[k];
    if (i < n) rowptr[i + 1] = run;
  }
  if (t == 255) partial[blockIdx.x] = sdata[255];
}

// Pass B: single block, exclusive scan of partials (nb <= 128).
__global__ void k_scan2(int* __restrict__ partial, int nb) {
  __shared__ int sdata[128];
  int t = threadIdx.x;
  int v = (t < nb) ? partial[t] : 0;
  sdata[t] = v;
  __syncthreads();
  for (int off = 1; off < 128; off <<= 1) {
    int x = (t >= off) ? sdata[t - off] : 0;
    __syncthreads();
    sdata[t] += x;
    __syncthreads();
  }
  if (t < nb) partial[t] = sdata[t] - v;  // exclusive
}

// Pass C: add chunk offsets; set rowptr[0]; cursor[i] = row start for scatter.
__global__ void k_scan3(int* __restrict__ rowptr, int* __restrict__ cursor,
                        const int* __restrict__ partial, int n) {
  int i = blockIdx.x * blockDim.x + threadIdx.x;
  if (i < n) {
    int c = cursor[i];  // still holds count
    int incl = rowptr[i + 1] + partial[i >> 10];
    rowptr[i + 1] = incl;
    cursor[i] = incl - c;  // exclusive start
  }
  if (i == 0) rowptr[0] = 0;
}

__global__ void k_scatter(const int* __restrict__ src, const int* __restrict__ dst,
                          const float* __restrict__ ew, int* __restrict__ cursor,
                          int* __restrict__ srcs, float* __restrict__ wss) {
  int i = blockIdx.x * blockDim.x + threadIdx.x;
  if (i < NE) {
    int d = dst[i];
    int p = atomicAdd(&cursor[d], 1);
    srcs[p] = src[i];
    wss[p] = ew[i];
  }
}

// ---------------- dense per-node GEMMs ----------------

// hp[n] = feat[n] @ W (DIM x DIM, row-major) + b   (no activation)
template <int DIM>
__global__ void k_gemm_p(const float* __restrict__ feat, const float* __restrict__ W,
                         const float* __restrict__ b, float* __restrict__ out, int n) {
  __shared__ __align__(16) float sW[DIM * DIM];
  __shared__ float sb[DIM];
  for (int i = threadIdx.x; i < DIM * DIM; i += blockDim.x) sW[i] = W[i];
  for (int i = threadIdx.x; i < DIM; i += blockDim.x) sb[i] = b[i];
  __syncthreads();
  int node = blockIdx.x * blockDim.x + threadIdx.x;
  if (node >= n) return;
  float f[DIM];
  const float4* fr = (const float4*)(feat + (size_t)node * DIM);
#pragma unroll
  for (int k = 0; k < DIM / 4; k++) {
    float4 t = fr[k];
    f[4 * k] = t.x; f[4 * k + 1] = t.y; f[4 * k + 2] = t.z; f[4 * k + 3] = t.w;
  }
  float4* op = (float4*)(out + (size_t)node * DIM);
#pragma unroll 1
  for (int j = 0; j < DIM; j += 4) {
    float4 acc = *(const float4*)(sb + j);
#pragma unroll
    for (int k = 0; k < DIM; k++) {
      float4 w4 = *(const float4*)(sW + k * DIM + j);
      acc.x += f[k] * w4.x; acc.y += f[k] * w4.y;
      acc.z += f[k] * w4.z; acc.w += f[k] * w4.w;
    }
    op[j / 4] = acc;
  }
}

// out[n] = relu(concat(feat[n], neigh[n]) @ W (2*DIN x 48) + b)
template <int DIN>
__global__ void k_gemm_n(const float* __restrict__ feat, const float* __restrict__ neigh,
                         const float* __restrict__ W, const float* __restrict__ b,
                         float* __restrict__ out, int n) {
  constexpr int DOUT = 48;
  constexpr int K = 2 * DIN;
  __shared__ __align__(16) float sW[K * DOUT];
  __shared__ float sb[DOUT];
  for (int i = threadIdx.x; i < K * DOUT; i += blockDim.x) sW[i] = W[i];
  for (int i = threadIdx.x; i < DOUT; i += blockDim.x) sb[i] = b[i];
  __syncthreads();
  int node = blockIdx.x * blockDim.x + threadIdx.x;
  if (node >= n) return;
  float f[K];
  const float4* fr = (const float4*)(feat + (size_t)node * DIN);
#pragma unroll
  for (int k = 0; k < DIN / 4; k++) {
    float4 t = fr[k];
    f[4 * k] = t.x; f[4 * k + 1] = t.y; f[4 * k + 2] = t.z; f[4 * k + 3] = t.w;
  }
  const float4* nr = (const float4*)(neigh + (size_t)node * DIN);
#pragma unroll
  for (int k = 0; k < DIN / 4; k++) {
    float4 t = nr[k];
    f[DIN + 4 * k] = t.x; f[DIN + 4 * k + 1] = t.y;
    f[DIN + 4 * k + 2] = t.z; f[DIN + 4 * k + 3] = t.w;
  }
  float4* op = (float4*)(out + (size_t)node * DOUT);
#pragma unroll 1
  for (int j = 0; j < DOUT; j += 4) {
    float4 acc = *(const float4*)(sb + j);
#pragma unroll
    for (int k = 0; k < K; k++) {
      float4 w4 = *(const float4*)(sW + k * DOUT + j);
      acc.x += f[k] * w4.x; acc.y += f[k] * w4.y;
      acc.z += f[k] * w4.z; acc.w += f[k] * w4.w;
    }
    acc.x = fmaxf(acc.x, 0.f); acc.y = fmaxf(acc.y, 0.f);
    acc.z = fmaxf(acc.z, 0.f); acc.w = fmaxf(acc.w, 0.f);
    op[j / 4] = acc;
  }
}

// ---------------- segment max (CSR, wave per node) ----------------

// DIM=48: lanes 0..47 own one feature each; 4-way edge unroll for MLP.
__global__ void k_segmax48(const float* __restrict__ hp, const int* __restrict__ rowptr,
                           const int* __restrict__ srcs, const float* __restrict__ wss,
                           float* __restrict__ neigh, int n) {
  int wave = (blockIdx.x * blockDim.x + threadIdx.x) >> 6;
  int lane = threadIdx.x & 63;
  if (wave >= n) return;
  int start = rowptr[wave], end = rowptr[wave + 1];
  bool act = lane < 48;
  float acc = -FLT_MAX;
  int e = start;
  for (; e + 4 <= end; e += 4) {
    int s0 = srcs[e], s1 = srcs[e + 1], s2 = srcs[e + 2], s3 = srcs[e + 3];
    float w0 = wss[e], w1 = wss[e + 1], w2 = wss[e + 2], w3 = wss[e + 3];
    if (act) {
      float v0 = hp[(size_t)s0 * 48 + lane] * w0;
      float v1 = hp[(size_t)s1 * 48 + lane] * w1;
      float v2 = hp[(size_t)s2 * 48 + lane] * w2;
      float v3 = hp[(size_t)s3 * 48 + lane] * w3;
      acc = fmaxf(acc, fmaxf(fmaxf(v0, v1), fmaxf(v2, v3)));
    }
  }
  for (; e < end; e++) {
    int s = srcs[e];
    float w = wss[e];
    if (act) acc = fmaxf(acc, hp[(size_t)s * 48 + lane] * w);
  }
  if (act) neigh[(size_t)wave * 48 + lane] = (end > start) ? acc : 0.0f;
}

// DIM=16: 4 edges per wave iteration (lane = 16*g + f), cross-group max via shfl.
__global__ void k_segmax16(const float* __restrict__ hp, const int* __restrict__ rowptr,
                           const int* __restrict__ srcs, const float* __restrict__ wss,
                           float* __restrict__ neigh, int n) {
  int wave = (blockIdx.x * blockDim.x + threadIdx.x) >> 6;
  int lane = threadIdx.x & 63;
  if (wave >= n) return;
  int start = rowptr[wave], end = rowptr[wave + 1];
  int g = lane >> 4, f = lane & 15;
  float acc = -FLT_MAX;
  for (int e = start + g; e < end; e += 4) {
    acc = fmaxf(acc, hp[(size_t)srcs[e] * 16 + f] * wss[e]);
  }
  acc = fmaxf(acc, __shfl_xor(acc, 16, 64));
  acc = fmaxf(acc, __shfl_xor(acc, 32, 64));
  if (lane < 16) neigh[(size_t)wave * 16 + lane] = (end > start) ? acc : 0.0f;
}

// ---------------- final epilogue ----------------

// delta[n] = sum over incoming edges of features[src][14] * w
__global__ void k_delta(const float* __restrict__ feat0, const int* __restrict__ rowptr,
                        const int* __restrict__ srcs, const float* __restrict__ wss,
                        float* __restrict__ delta, int n) {
  int i = blockIdx.x * blockDim.x + threadIdx.x;
  if (i >= n) return;
  int s = rowptr[i], e = rowptr[i + 1];
  float acc = 0.f;
  for (int k = s; k < e; k++) acc += feat0[(size_t)srcs[k] * 16 + 14] * wss[k];
  delta[i] = acc;
}

// out = min(now + relu(concat(feat48, neigh48) @ Wn2 + bn2), clip(now + delta, 0, 1))
__global__ void k_final(const float* __restrict__ feat48, const float* __restrict__ neigh48,
                        const float* __restrict__ Wn, const float* __restrict__ bn,
                        const float* __restrict__ feat0, const float* __restrict__ delta,
                        float* __restrict__ out, int n) {
  __shared__ __align__(16) float sW[96];
  __shared__ float sb;
  if (threadIdx.x < 96) sW[threadIdx.x] = Wn[threadIdx.x];
  if (threadIdx.x == 0) sb = bn[0];
  __syncthreads();
  int i = blockIdx.x * blockDim.x + threadIdx.x;
  if (i >= n) return;
  float acc = sb;
  const float4* a = (const float4*)(feat48 + (size_t)i * 48);
#pragma unroll
  for (int k = 0; k < 12; k++) {
    float4 t = a[k];
    acc += t.x * sW[4 * k] + t.y * sW[4 * k + 1] + t.z * sW[4 * k + 2] + t.w * sW[4 * k + 3];
  }
  const float4* b2 = (const float4*)(neigh48 + (size_t)i * 48);
#pragma unroll
  for (int k = 0; k < 12; k++) {
    float4 t = b2[k];
    acc += t.x * sW[48 + 4 * k] + t.y * sW[48 + 4 * k + 1] +
           t.z * sW[48 + 4 * k + 2] + t.w * sW[48 + 4 * k + 3];
  }
  float h = fmaxf(acc, 0.f);
  float now = feat0[(size_t)i * 16 + 15];
  float ub = fminf(fmaxf(now + delta[i], 0.f), 1.f);
  out[i] = fminf(now + h, ub);
}

// ---------------- launch ----------------

extern "C" void kernel_launch(void* const* d_in, const int* in_sizes, int n_in,
                              void* d_out, int out_size, void* d_ws, size_t ws_size,
                              hipStream_t stream) {
  const float* features = (const float*)d_in[0];
  const float* ew = (const float*)d_in[1];
  const int* src = (const int*)d_in[2];
  const int* dst = (const int*)d_in[3];
  const float* Wp0 = (const float*)d_in[4];  const float* bp0 = (const float*)d_in[5];
  const float* Wn0 = (const float*)d_in[6];  const float* bn0 = (const float*)d_in[7];
  const float* Wp1 = (const float*)d_in[8];  const float* bp1 = (const float*)d_in[9];
  const float* Wn1 = (const float*)d_in[10]; const float* bn1 = (const float*)d_in[11];
  const float* Wp2 = (const float*)d_in[12]; const float* bp2 = (const float*)d_in[13];
  const float* Wn2 = (const float*)d_in[14]; const float* bn2 = (const float*)d_in[15];
  float* out = (float*)d_out;

  // workspace carve-up (~91 MB total)
  char* base = (char*)d_ws;
  size_t off = 0;
  auto take = [&](size_t bytes) -> void* {
    void* p = base + off;
    off += (bytes + 255) & ~(size_t)255;
    return p;
  };
  float* hp     = (float*)take((size_t)NN * 48 * 4);
  float* neigh  = (float*)take((size_t)NN * 48 * 4);
  float* bufA   = (float*)take((size_t)NN * 48 * 4);
  float* bufB   = (float*)take((size_t)NN * 48 * 4);
  int*   rowptr = (int*)take((size_t)(NN + 1) * 4);
  int*   cursor = (int*)take((size_t)NN * 4);
  int*   srcs   = (int*)take((size_t)NE * 4);
  float* wss    = (float*)take((size_t)NE * 4);
  int*   partial= (int*)take(4096);
  float* delta  = (float*)take((size_t)NN * 4);
  (void)ws_size; (void)in_sizes; (void)n_in; (void)out_size;

  const int B = 256;
  int nbE = (NE + B - 1) / B;          // 6250
  int nbN = (NN + B - 1) / B;          // 391
  int nbW = (NN * 64 + B - 1) / B;     // 25000 (wave per node)
  int nScan = (NN + 1023) / 1024;      // 98

  // CSR build (reused by all 3 layers + delta)
  k_zero_int<<<nbN, B, 0, stream>>>(cursor, NN);
  k_count<<<nbE, B, 0, stream>>>(dst, cursor);
  k_scan1<<<nScan, B, 0, stream>>>(cursor, rowptr, partial, NN);
  k_scan2<<<1, 128, 0, stream>>>(partial, nScan);
  k_scan3<<<nbN, B, 0, stream>>>(rowptr, cursor, partial, NN);
  k_scatter<<<nbE, B, 0, stream>>>(src, dst, ew, cursor, srcs, wss);

  // delta_ub segment-sum (independent of conv layers)
  k_delta<<<nbN, B, 0, stream>>>(features, rowptr, srcs, wss, delta, NN);

  // layer 0: 16 -> 48
  k_gemm_p<16><<<nbN, B, 0, stream>>>(features, Wp0, bp0, hp, NN);
  k_segmax16<<<nbW, B, 0, stream>>>(hp, rowptr, srcs, wss, neigh, NN);
  k_gemm_n<16><<<nbN, B, 0, stream>>>(features, neigh, Wn0, bn0, bufA, NN);

  // layer 1: 48 -> 48
  k_gemm_p<48><<<nbN, B, 0, stream>>>(bufA, Wp1, bp1, hp, NN);
  k_segmax48<<<nbW, B, 0, stream>>>(hp, rowptr, srcs, wss, neigh, NN);
  k_gemm_n<48><<<nbN, B, 0, stream>>>(bufA, neigh, Wn1, bn1, bufB, NN);

  // layer 2: 48 -> 1, fused with epilogue
  k_gemm_p<48><<<nbN, B, 0, stream>>>(bufB, Wp2, bp2, hp, NN);
  k_segmax48<<<nbW, B, 0, stream>>>(hp, rowptr, srcs, wss, neigh, NN);
  k_final<<<nbN, B, 0, stream>>>(bufB, neigh, Wn2, bn2, features, delta, out, NN);
}